// Round 3
// baseline (4586.456 us; speedup 1.0000x reference)
//
#include <hip/hip_runtime.h>
#include <hip/hip_bf16.h>

#define B_ 64
#define T_ 256
#define H_ 1024
#define NKK_ 40  // K/32 = 1280/32

typedef __attribute__((ext_vector_type(8))) short short8;
typedef __attribute__((ext_vector_type(4))) float float4_;
typedef unsigned long long u64;

static __device__ __forceinline__ ushort f2bf(float v) {
  __hip_bfloat16 b = __float2bfloat16(v);
  return *reinterpret_cast<ushort*>(&b);
}
static __device__ __forceinline__ float sigm(float v) { return 1.0f / (1.0f + __expf(-v)); }
static __device__ __forceinline__ float tanh_fast(float v) {
  float e = __expf(2.0f * v);
  return 1.0f - 2.0f / (e + 1.0f);  // inf-safe at both ends
}

// Xall[t][b][j] bf16: j even = x[b][j/2][t], j odd = y[b][j/2][t-1] (0 at t=0)
__global__ __launch_bounds__(256) void build_X(const float* __restrict__ x,
                                               const float* __restrict__ y,
                                               ushort* __restrict__ Xall) {
  __shared__ float xl[128][33];
  __shared__ float yl[128][33];
  int b = blockIdx.x >> 3;
  int t0 = (blockIdx.x & 7) * 32;
  int tid = threadIdx.x;
  for (int it = 0; it < 16; ++it) {
    int idx = it * 256 + tid;
    int s = idx >> 5, tt = idx & 31;
    xl[s][tt] = x[((size_t)b * 128 + s) * T_ + t0 + tt];
    int ty = t0 + tt - 1;
    yl[s][tt] = (ty >= 0) ? y[((size_t)b * 128 + s) * T_ + ty] : 0.0f;
  }
  __syncthreads();
  for (int tt = 0; tt < 32; ++tt) {
    float v = (tid & 1) ? yl[tid >> 1][tt] : xl[tid >> 1][tt];
    Xall[((size_t)(t0 + tt) * B_ + b) * 256 + tid] = f2bf(v);
  }
}

// Bp[(nb*40+kk)*64 + l][8]: lane l supplies B[k=32kk+8*(l>>4)+j][localcol=l&15]
// localcol q -> gate g=q>>2, hcol m=q&3; col = nb*4+m of gate g's W
__global__ __launch_bounds__(256) void prep_weights(const float* __restrict__ Wf,
                                                    const float* __restrict__ Wi,
                                                    const float* __restrict__ Wu,
                                                    const float* __restrict__ Wo,
                                                    ushort* __restrict__ Bp) {
  int flat = blockIdx.x * 256 + threadIdx.x;
  int l = flat & 63;
  int g2 = flat >> 6;
  int kk = g2 % NKK_;
  int nb = g2 / NKK_;
  int q = l & 15, kg = l >> 4;
  int g = q >> 2, m = q & 3;
  const float* W = (g == 0) ? Wf : (g == 1) ? Wi : (g == 2) ? Wu : Wo;
  int col = nb * 4 + m;
  ushort tmp[8];
#pragma unroll
  for (int j = 0; j < 8; ++j) {
    int k = kk * 32 + kg * 8 + j;
    tmp[j] = f2bf(W[(size_t)k * H_ + col]);
  }
  *(short8*)(Bp + (size_t)flat * 8) = *(short8*)tmp;
}

// Persistent LSTM: 256 blocks x 1024 threads, whole T loop in-kernel.
// COH=true : Hh has T+1 slots (fresh addresses -> plain loads safe)
// COH=false: Hh has 2 slots, h loads use agent-scope atomics (LLC-coherent)
template <bool COH>
__global__ __launch_bounds__(1024) void lstm_persist(
    const ushort* __restrict__ Xall, const ushort* __restrict__ Bp,
    const float* __restrict__ bfp, const float* __restrict__ bip,
    const float* __restrict__ bup, const float* __restrict__ bop,
    ushort* __restrict__ Hh, float* __restrict__ out,
    unsigned int* __restrict__ bar) {
  __shared__ float gbuf[4][4][16][17];  // [kq][mt][row][col] K-split partials
  __shared__ float hbuf[4][64][37];     // [m][bb][t&31] out-burst buffer (37-pad)
  const int tid = threadIdx.x;
  const int w = tid >> 6, l = tid & 63;
  const int mt = w & 3, kq = w >> 2;
  const int ar = l & 15, kg = l >> 4;
  const int bA = mt * 16 + ar;
  const int nb = blockIdx.x;

  // ---- B fragments: load once into registers (40 VGPR) ----
  short8 bfrag[10];
  {
    const ushort* bp = Bp + (((size_t)nb * NKK_ + kq * 10) * 64 + l) * 8;
#pragma unroll
    for (int u = 0; u < 10; ++u) bfrag[u] = *(const short8*)(bp + (size_t)u * 64 * 8);
  }

  const int bb = tid & 63, m = (tid >> 6) & 3;
  const int hcol = nb * 4 + m;
  float biasF = 0, biasI = 0, biasU = 0, biasO = 0, creg = 0;
  if (tid < 256) {
    biasF = bfp[hcol]; biasI = bip[hcol]; biasU = bup[hcol]; biasO = bop[hcol];
  }

  for (int t = 0; t < T_; ++t) {
    const ushort* xrow = Xall + ((size_t)t * B_ + bA) * 256 + kg * 8;
    const ushort* hrow = Hh + ((size_t)(COH ? t : (t & 1)) * B_ + bA) * H_ + kg * 8;
    float4_ acc = {0.f, 0.f, 0.f, 0.f};
#pragma unroll
    for (int u = 0; u < 10; ++u) {
      int kk = kq * 10 + u;
      short8 av;
      if (kk < 8) {
        av = *(const short8*)(xrow + kk * 32);
      } else if (COH) {
        av = *(const short8*)(hrow + (kk - 8) * 32);
      } else {
        const u64* p = (const u64*)(hrow + (kk - 8) * 32);
        union { u64 q[2]; short8 s; } cv;
        cv.q[0] = __hip_atomic_load(p, __ATOMIC_RELAXED, __HIP_MEMORY_SCOPE_AGENT);
        cv.q[1] = __hip_atomic_load(p + 1, __ATOMIC_RELAXED, __HIP_MEMORY_SCOPE_AGENT);
        av = cv.s;
      }
      acc = __builtin_amdgcn_mfma_f32_16x16x32_bf16(av, bfrag[u], acc, 0, 0, 0);
    }
    {
      int rbase = kg * 4;
#pragma unroll
      for (int r = 0; r < 4; ++r) gbuf[kq][mt][rbase + r][ar] = acc[r];
    }
    __syncthreads();
    if (tid < 256) {
      int row = bb & 15, mtt = bb >> 4;
      float f = 0, i = 0, uu = 0, o = 0;
#pragma unroll
      for (int k2 = 0; k2 < 4; ++k2) {
        f  += gbuf[k2][mtt][row][m];
        i  += gbuf[k2][mtt][row][4 + m];
        uu += gbuf[k2][mtt][row][8 + m];
        o  += gbuf[k2][mtt][row][12 + m];
      }
      f += biasF; i += biasI; uu += biasU; o += biasO;
      creg = fmaf(creg, sigm(f), sigm(i) * tanh_fast(uu));
      float h = sigm(o) * tanh_fast(creg);
      hbuf[m][bb][t & 31] = h;
      if ((t & 31) == 31) {  // coalesced 128 B burst per thread
        float* orow = out + ((size_t)bb * H_ + hcol) * T_ + (t - 31);
#pragma unroll
        for (int tt = 0; tt < 32; tt += 4) {
          float4 v = {hbuf[m][bb][tt], hbuf[m][bb][tt + 1],
                      hbuf[m][bb][tt + 2], hbuf[m][bb][tt + 3]};
          *(float4*)(orow + tt) = v;
        }
      }
      // h for next step: write-through to LLC (cross-XCD visible)
      unsigned short* hp = (unsigned short*)(Hh +
          ((size_t)(COH ? (t + 1) : ((t + 1) & 1)) * B_ + bb) * H_ + hcol);
      __hip_atomic_store(hp, f2bf(h), __ATOMIC_RELAXED, __HIP_MEMORY_SCOPE_AGENT);
    }
    __syncthreads();  // all waves' stores drained (vmcnt) before arrival
    if (tid == 0) {
      unsigned int tgt = 16u * (unsigned)(t + 1);
      __hip_atomic_fetch_add(&bar[(nb & 15) * 32], 1u, __ATOMIC_RELEASE,
                             __HIP_MEMORY_SCOPE_AGENT);
#pragma unroll 1
      for (int i2 = 0; i2 < 16; ++i2)
        while (__hip_atomic_load(&bar[i2 * 32], __ATOMIC_RELAXED,
                                 __HIP_MEMORY_SCOPE_AGENT) < tgt)
          __builtin_amdgcn_s_sleep(1);
      __builtin_amdgcn_fence(__ATOMIC_ACQUIRE, "agent");
    }
    __syncthreads();
  }
  if (tid < 256) out[(size_t)B_ * H_ * T_ + (size_t)bb * H_ + hcol] = creg;
}

extern "C" void kernel_launch(void* const* d_in, const int* in_sizes, int n_in,
                              void* d_out, int out_size, void* d_ws, size_t ws_size,
                              hipStream_t stream) {
  const float* x  = (const float*)d_in[0];
  const float* y  = (const float*)d_in[2];
  const float* Wf = (const float*)d_in[3];  const float* bf = (const float*)d_in[4];
  const float* Wi = (const float*)d_in[5];  const float* bi = (const float*)d_in[6];
  const float* Wu = (const float*)d_in[7];  const float* bu = (const float*)d_in[8];
  const float* Wo = (const float*)d_in[9];  const float* bo = (const float*)d_in[10];
  float* out = (float*)d_out;

  char* p = (char*)d_ws;
  ushort* Bp = (ushort*)p;        p += (size_t)256 * NKK_ * 64 * 8 * 2;  // 10.49 MB
  ushort* Xall = (ushort*)p;      p += (size_t)T_ * B_ * 256 * 2;        // 8.39 MB
  unsigned int* bar = (unsigned int*)p; p += 2048;                       // 16x128B
  ushort* Hh = (ushort*)p;
  size_t head = (size_t)(p - (char*)d_ws);
  bool coh = ws_size >= head + (size_t)(T_ + 1) * B_ * H_ * 2;

  prep_weights<<<(256 * NKK_ * 64) / 256, 256, 0, stream>>>(Wf, Wi, Wu, Wo, Bp);
  build_X<<<B_ * 8, 256, 0, stream>>>(x, y, Xall);
  hipMemsetAsync(bar, 0, 2048, stream);
  hipMemsetAsync(Hh, 0, (size_t)B_ * H_ * 2, stream);  // slot 0 = h_{-1} = 0

  if (coh)
    lstm_persist<true><<<256, 1024, 0, stream>>>(Xall, Bp, bf, bi, bu, bo, Hh, out, bar);
  else
    lstm_persist<false><<<256, 1024, 0, stream>>>(Xall, Bp, bf, bi, bu, bo, Hh, out, bar);
}

// Round 4
// 3045.344 us; speedup vs baseline: 1.5061x; 1.5061x over previous
//
#include <hip/hip_runtime.h>
#include <hip/hip_bf16.h>

#define B_ 64
#define T_ 256
#define H_ 1024
#define NKK_ 40  // K/32 = 1280/32

typedef __attribute__((ext_vector_type(8))) short short8;
typedef __attribute__((ext_vector_type(4))) float float4_;
typedef unsigned long long u64;

static __device__ __forceinline__ ushort f2bf(float v) {
  __hip_bfloat16 b = __float2bfloat16(v);
  return *reinterpret_cast<ushort*>(&b);
}
static __device__ __forceinline__ float sigm(float v) { return 1.0f / (1.0f + __expf(-v)); }
static __device__ __forceinline__ float tanh_fast(float v) {
  float e = __expf(2.0f * v);
  return 1.0f - 2.0f / (e + 1.0f);  // inf-safe at both ends
}

// Xall[t][b][j] bf16: j even = x[b][j/2][t], j odd = y[b][j/2][t-1] (0 at t=0)
__global__ __launch_bounds__(256) void build_X(const float* __restrict__ x,
                                               const float* __restrict__ y,
                                               ushort* __restrict__ Xall) {
  __shared__ float xl[128][33];
  __shared__ float yl[128][33];
  int b = blockIdx.x >> 3;
  int t0 = (blockIdx.x & 7) * 32;
  int tid = threadIdx.x;
  for (int it = 0; it < 16; ++it) {
    int idx = it * 256 + tid;
    int s = idx >> 5, tt = idx & 31;
    xl[s][tt] = x[((size_t)b * 128 + s) * T_ + t0 + tt];
    int ty = t0 + tt - 1;
    yl[s][tt] = (ty >= 0) ? y[((size_t)b * 128 + s) * T_ + ty] : 0.0f;
  }
  __syncthreads();
  for (int tt = 0; tt < 32; ++tt) {
    float v = (tid & 1) ? yl[tid >> 1][tt] : xl[tid >> 1][tt];
    Xall[((size_t)(t0 + tt) * B_ + b) * 256 + tid] = f2bf(v);
  }
}

// Bp[(nb*40+kk)*64 + l][8]: lane l supplies B[k=32kk+8*(l>>4)+j][localcol=l&15]
// localcol q -> gate g=q>>2, hcol m=q&3; col = nb*4+m of gate g's W
__global__ __launch_bounds__(256) void prep_weights(const float* __restrict__ Wf,
                                                    const float* __restrict__ Wi,
                                                    const float* __restrict__ Wu,
                                                    const float* __restrict__ Wo,
                                                    ushort* __restrict__ Bp) {
  int flat = blockIdx.x * 256 + threadIdx.x;
  int l = flat & 63;
  int g2 = flat >> 6;
  int kk = g2 % NKK_;
  int nb = g2 / NKK_;
  int q = l & 15, kg = l >> 4;
  int g = q >> 2, m = q & 3;
  const float* W = (g == 0) ? Wf : (g == 1) ? Wi : (g == 2) ? Wu : Wo;
  int col = nb * 4 + m;
  ushort tmp[8];
#pragma unroll
  for (int j = 0; j < 8; ++j) {
    int k = kk * 32 + kg * 8 + j;
    tmp[j] = f2bf(W[(size_t)k * H_ + col]);
  }
  *(short8*)(Bp + (size_t)flat * 8) = *(short8*)tmp;
}

// Persistent LSTM: 256 blocks x 1024 threads, whole T loop in-kernel.
// h ping-pongs through 2 slots with sc1 (agent-scope) loads/stores: always
// LLC-coherent, never stale, replay-safe. No cache-invalidating fences in
// the loop, so Bp/Xall/bias stay L2-resident.
__global__ __launch_bounds__(1024) void lstm_persist(
    const ushort* __restrict__ Xall, const ushort* __restrict__ Bp,
    const float* __restrict__ bfp, const float* __restrict__ bip,
    const float* __restrict__ bup, const float* __restrict__ bop,
    ushort* __restrict__ Hh, float* __restrict__ out,
    unsigned int* __restrict__ bar) {
  __shared__ float gbuf[4][4][16][17];  // [kq][mt][row][col] K-split partials
  __shared__ float hbuf[4][64][37];     // [m][bb][t&31] out-burst buffer
  const int tid = threadIdx.x;
  const int w = tid >> 6, l = tid & 63;
  const int mt = w & 3, kq = w >> 2;
  const int ar = l & 15, kg = l >> 4;
  const int bA = mt * 16 + ar;
  const int nb = blockIdx.x;

  // B fragments (compiler may keep in regs or re-load from L2; both fine)
  short8 bfrag[10];
  {
    const ushort* bp = Bp + (((size_t)nb * NKK_ + kq * 10) * 64 + l) * 8;
#pragma unroll
    for (int u = 0; u < 10; ++u) bfrag[u] = *(const short8*)(bp + (size_t)u * 64 * 8);
  }

  const int bb = tid & 63, m = (tid >> 6) & 3;
  const int hcol = nb * 4 + m;
  float biasF = 0, biasI = 0, biasU = 0, biasO = 0, creg = 0;
  if (tid < 256) {
    biasF = bfp[hcol]; biasI = bip[hcol]; biasU = bup[hcol]; biasO = bop[hcol];
  }

  for (int t = 0; t < T_; ++t) {
    const ushort* xrow = Xall + ((size_t)t * B_ + bA) * 256 + kg * 8;
    const ushort* hrow = Hh + ((size_t)(t & 1) * B_ + bA) * H_ + kg * 8;
    float4_ acc = {0.f, 0.f, 0.f, 0.f};
#pragma unroll
    for (int u = 0; u < 10; ++u) {
      int kk = kq * 10 + u;
      short8 av;
      if (kk < 8) {
        av = *(const short8*)(xrow + kk * 32);
      } else {
        const u64* p = (const u64*)(hrow + (kk - 8) * 32);
        union { u64 q[2]; short8 s; } cv;
        cv.q[0] = __hip_atomic_load(p, __ATOMIC_RELAXED, __HIP_MEMORY_SCOPE_AGENT);
        cv.q[1] = __hip_atomic_load(p + 1, __ATOMIC_RELAXED, __HIP_MEMORY_SCOPE_AGENT);
        av = cv.s;
      }
      acc = __builtin_amdgcn_mfma_f32_16x16x32_bf16(av, bfrag[u], acc, 0, 0, 0);
    }
    {
      int rbase = kg * 4;
#pragma unroll
      for (int r = 0; r < 4; ++r) gbuf[kq][mt][rbase + r][ar] = acc[r];
    }
    __syncthreads();
    if (tid < 256) {
      int row = bb & 15, mtt = bb >> 4;
      float f = 0, i = 0, uu = 0, o = 0;
#pragma unroll
      for (int k2 = 0; k2 < 4; ++k2) {
        f  += gbuf[k2][mtt][row][m];
        i  += gbuf[k2][mtt][row][4 + m];
        uu += gbuf[k2][mtt][row][8 + m];
        o  += gbuf[k2][mtt][row][12 + m];
      }
      f += biasF; i += biasI; uu += biasU; o += biasO;
      creg = fmaf(creg, sigm(f), sigm(i) * tanh_fast(uu));
      float h = sigm(o) * tanh_fast(creg);
      hbuf[m][bb][t & 31] = h;
      if ((t & 31) == 31) {  // coalesced 128 B burst per thread
        float* orow = out + ((size_t)bb * H_ + hcol) * T_ + (t - 31);
#pragma unroll
        for (int tt = 0; tt < 32; tt += 4) {
          float4 v = {hbuf[m][bb][tt], hbuf[m][bb][tt + 1],
                      hbuf[m][bb][tt + 2], hbuf[m][bb][tt + 3]};
          *(float4*)(orow + tt) = v;
        }
      }
      // h for next step: sc1 write-through, visible at LLC once vmcnt drains
      unsigned short* hp = (unsigned short*)(Hh +
          ((size_t)((t + 1) & 1) * B_ + bb) * H_ + hcol);
      __hip_atomic_store(hp, f2bf(h), __ATOMIC_RELAXED, __HIP_MEMORY_SCOPE_AGENT);
    }
    __syncthreads();  // drains all waves' vmcnt: h stores ack'd at LLC
    if (tid == 0) {
      // two-level arrival, single-flag spin (one LLC line polled)
      unsigned int tgt = (unsigned int)(t + 1);
      unsigned int r1 = __hip_atomic_fetch_add(&bar[(nb & 15) * 32], 1u,
                                               __ATOMIC_RELAXED, __HIP_MEMORY_SCOPE_AGENT);
      if (r1 == 16u * tgt - 1u) {
        unsigned int r2 = __hip_atomic_fetch_add(&bar[16 * 32], 1u,
                                                 __ATOMIC_RELAXED, __HIP_MEMORY_SCOPE_AGENT);
        if (r2 == 16u * tgt - 1u)
          __hip_atomic_store(&bar[17 * 32], tgt, __ATOMIC_RELAXED,
                             __HIP_MEMORY_SCOPE_AGENT);
      }
      while (__hip_atomic_load(&bar[17 * 32], __ATOMIC_RELAXED,
                               __HIP_MEMORY_SCOPE_AGENT) < tgt)
        __builtin_amdgcn_s_sleep(1);
      asm volatile("" ::: "memory");
    }
    __syncthreads();
  }
  if (tid < 256) out[(size_t)B_ * H_ * T_ + (size_t)bb * H_ + hcol] = creg;
}

extern "C" void kernel_launch(void* const* d_in, const int* in_sizes, int n_in,
                              void* d_out, int out_size, void* d_ws, size_t ws_size,
                              hipStream_t stream) {
  const float* x  = (const float*)d_in[0];
  const float* y  = (const float*)d_in[2];
  const float* Wf = (const float*)d_in[3];  const float* bf = (const float*)d_in[4];
  const float* Wi = (const float*)d_in[5];  const float* bi = (const float*)d_in[6];
  const float* Wu = (const float*)d_in[7];  const float* bu = (const float*)d_in[8];
  const float* Wo = (const float*)d_in[9];  const float* bo = (const float*)d_in[10];
  float* out = (float*)d_out;

  char* p = (char*)d_ws;
  ushort* Bp = (ushort*)p;        p += (size_t)256 * NKK_ * 64 * 8 * 2;  // 10.49 MB
  ushort* Xall = (ushort*)p;      p += (size_t)T_ * B_ * 256 * 2;        // 8.39 MB
  unsigned int* bar = (unsigned int*)p; p += 4096;
  ushort* Hh = (ushort*)p;        // 2 slots x 128 KB ping-pong

  prep_weights<<<(256 * NKK_ * 64) / 256, 256, 0, stream>>>(Wf, Wi, Wu, Wo, Bp);
  build_X<<<B_ * 8, 256, 0, stream>>>(x, y, Xall);
  hipMemsetAsync(bar, 0, 4096, stream);
  hipMemsetAsync(Hh, 0, (size_t)B_ * H_ * 2, stream);  // slot 0 = h_{-1} = 0

  lstm_persist<<<256, 1024, 0, stream>>>(Xall, Bp, bf, bi, bu, bo, Hh, out, bar);
}

// Round 5
// 2829.559 us; speedup vs baseline: 1.6209x; 1.0763x over previous
//
#include <hip/hip_runtime.h>
#include <hip/hip_bf16.h>

#define B_ 64
#define T_ 256
#define H_ 1024
#define NKK_ 40  // K/32 = 1280/32
#define NB_ 256  // grid size (must stay 256: flag gather reads 256 words)

typedef __attribute__((ext_vector_type(8))) short short8;
typedef __attribute__((ext_vector_type(4))) float float4_;
typedef unsigned long long u64;

static __device__ __forceinline__ ushort f2bf(float v) {
  __hip_bfloat16 b = __float2bfloat16(v);
  return *reinterpret_cast<ushort*>(&b);
}
static __device__ __forceinline__ float sigm(float v) { return 1.0f / (1.0f + __expf(-v)); }
static __device__ __forceinline__ float tanh_fast(float v) {
  float e = __expf(2.0f * v);
  return 1.0f - 2.0f / (e + 1.0f);  // inf-safe at both ends
}

// Xall[t][b][j] bf16: j even = x[b][j/2][t], j odd = y[b][j/2][t-1] (0 at t=0)
__global__ __launch_bounds__(256) void build_X(const float* __restrict__ x,
                                               const float* __restrict__ y,
                                               ushort* __restrict__ Xall) {
  __shared__ float xl[128][33];
  __shared__ float yl[128][33];
  int b = blockIdx.x >> 3;
  int t0 = (blockIdx.x & 7) * 32;
  int tid = threadIdx.x;
  for (int it = 0; it < 16; ++it) {
    int idx = it * 256 + tid;
    int s = idx >> 5, tt = idx & 31;
    xl[s][tt] = x[((size_t)b * 128 + s) * T_ + t0 + tt];
    int ty = t0 + tt - 1;
    yl[s][tt] = (ty >= 0) ? y[((size_t)b * 128 + s) * T_ + ty] : 0.0f;
  }
  __syncthreads();
  for (int tt = 0; tt < 32; ++tt) {
    float v = (tid & 1) ? yl[tid >> 1][tt] : xl[tid >> 1][tt];
    Xall[((size_t)(t0 + tt) * B_ + b) * 256 + tid] = f2bf(v);
  }
}

// Bp[(nb*40+kk)*64 + l][8]: lane l supplies B[k=32kk+8*(l>>4)+j][localcol=l&15]
// localcol q -> gate g=q>>2, hcol m=q&3; col = nb*4+m of gate g's W
__global__ __launch_bounds__(256) void prep_weights(const float* __restrict__ Wf,
                                                    const float* __restrict__ Wi,
                                                    const float* __restrict__ Wu,
                                                    const float* __restrict__ Wo,
                                                    ushort* __restrict__ Bp) {
  int flat = blockIdx.x * 256 + threadIdx.x;
  int l = flat & 63;
  int g2 = flat >> 6;
  int kk = g2 % NKK_;
  int nb = g2 / NKK_;
  int q = l & 15, kg = l >> 4;
  int g = q >> 2, m = q & 3;
  const float* W = (g == 0) ? Wf : (g == 1) ? Wi : (g == 2) ? Wu : Wo;
  int col = nb * 4 + m;
  ushort tmp[8];
#pragma unroll
  for (int j = 0; j < 8; ++j) {
    int k = kk * 32 + kg * 8 + j;
    tmp[j] = f2bf(W[(size_t)k * H_ + col]);
  }
  *(short8*)(Bp + (size_t)flat * 8) = *(short8*)tmp;
}

// Persistent LSTM: 256 blocks x 1024 threads, whole T loop in-kernel.
// h ping-pongs through 2 LLC-coherent slots (sc1 atomics). Barrier = flag
// array (one sc1 word per block) + wave-gather poll: no atomics, one LLC
// latency per poll round. x-part MFMAs overlap the wait.
__global__ __launch_bounds__(1024) void lstm_persist(
    const ushort* __restrict__ Xall, const ushort* __restrict__ Bp,
    const float* __restrict__ bfp, const float* __restrict__ bip,
    const float* __restrict__ bup, const float* __restrict__ bop,
    ushort* __restrict__ Hh, float* __restrict__ out,
    unsigned int* __restrict__ flags) {
  __shared__ float gbuf[4][4][16][17];  // [kq][mt][row][col] K-split partials
  __shared__ float hbuf[4][64][33];     // [m][bb][t&31] out-burst buffer
  const int tid = threadIdx.x;
  const int w = tid >> 6, l = tid & 63;
  const int mt = w & 3, kq = w >> 2;
  const int ar = l & 15, kg = l >> 4;
  const int bA = mt * 16 + ar;
  const int nb = blockIdx.x;

  // K-slice remap: wave kq owns x-slices {2kq, 2kq+1}, h-slices {8+8kq..15+8kq}
  // B fragments loaded once and PINNED in VGPRs (asm blocks rematerialization)
  short8 bfrag[10];
  {
    const ushort* bp0 = Bp + ((size_t)nb * NKK_ * 64 + l) * 8;
#pragma unroll
    for (int u = 0; u < 2; ++u)
      bfrag[u] = *(const short8*)(bp0 + (size_t)(2 * kq + u) * 64 * 8);
#pragma unroll
    for (int u = 2; u < 10; ++u)
      bfrag[u] = *(const short8*)(bp0 + (size_t)(8 + 8 * kq + (u - 2)) * 64 * 8);
  }
#pragma unroll
  for (int u = 0; u < 10; ++u) asm volatile("" : "+v"(bfrag[u]));

  const int bb = tid & 63, m = (tid >> 6) & 3;
  const int hcol = nb * 4 + m;
  float biasF = 0, biasI = 0, biasU = 0, biasO = 0, creg = 0;
  if (tid < 256) {
    biasF = bfp[hcol]; biasI = bip[hcol]; biasU = bup[hcol]; biasO = bop[hcol];
  }

  for (int t = 0; t < T_; ++t) {
    // ---- x-part: 2 MFMAs, no dependence on the barrier ----
    const ushort* xrow = Xall + ((size_t)t * B_ + bA) * 256 + kg * 8;
    float4_ acc = {0.f, 0.f, 0.f, 0.f};
#pragma unroll
    for (int u = 0; u < 2; ++u) {
      short8 av = *(const short8*)(xrow + (2 * kq + u) * 32);
      acc = __builtin_amdgcn_mfma_f32_16x16x32_bf16(av, bfrag[u], acc, 0, 0, 0);
    }
    // ---- wait for h(t): wave0 gathers all 256 flags (4 indep loads/lane) ----
    if (t > 0 && tid < 64) {
      unsigned int tgt = (unsigned int)t;
      for (;;) {
        unsigned int f0 = __hip_atomic_load(&flags[l * 4 + 0], __ATOMIC_RELAXED,
                                            __HIP_MEMORY_SCOPE_AGENT);
        unsigned int f1 = __hip_atomic_load(&flags[l * 4 + 1], __ATOMIC_RELAXED,
                                            __HIP_MEMORY_SCOPE_AGENT);
        unsigned int f2 = __hip_atomic_load(&flags[l * 4 + 2], __ATOMIC_RELAXED,
                                            __HIP_MEMORY_SCOPE_AGENT);
        unsigned int f3 = __hip_atomic_load(&flags[l * 4 + 3], __ATOMIC_RELAXED,
                                            __HIP_MEMORY_SCOPE_AGENT);
        bool ok = (f0 >= tgt) & (f1 >= tgt) & (f2 >= tgt) & (f3 >= tgt);
        if (__all(ok)) break;
        __builtin_amdgcn_s_sleep(2);
      }
    }
    __syncthreads();
    // ---- h-part: 8 MFMAs, h read sc1 (LLC-coherent) ----
    const ushort* hrow = Hh + ((size_t)(t & 1) * B_ + bA) * H_ + kg * 8;
#pragma unroll
    for (int u = 2; u < 10; ++u) {
      const u64* p = (const u64*)(hrow + (8 * kq + (u - 2)) * 32);
      union { u64 q[2]; short8 s; } cv;
      cv.q[0] = __hip_atomic_load(p, __ATOMIC_RELAXED, __HIP_MEMORY_SCOPE_AGENT);
      cv.q[1] = __hip_atomic_load(p + 1, __ATOMIC_RELAXED, __HIP_MEMORY_SCOPE_AGENT);
      acc = __builtin_amdgcn_mfma_f32_16x16x32_bf16(cv.s, bfrag[u], acc, 0, 0, 0);
    }
    {
      int rbase = kg * 4;
#pragma unroll
      for (int r = 0; r < 4; ++r) gbuf[kq][mt][rbase + r][ar] = acc[r];
    }
    __syncthreads();
    if (tid < 256) {
      int row = bb & 15, mtt = bb >> 4;
      float f = 0, i = 0, uu = 0, o = 0;
#pragma unroll
      for (int k2 = 0; k2 < 4; ++k2) {
        f  += gbuf[k2][mtt][row][m];
        i  += gbuf[k2][mtt][row][4 + m];
        uu += gbuf[k2][mtt][row][8 + m];
        o  += gbuf[k2][mtt][row][12 + m];
      }
      f += biasF; i += biasI; uu += biasU; o += biasO;
      creg = fmaf(creg, sigm(f), sigm(i) * tanh_fast(uu));
      float h = sigm(o) * tanh_fast(creg);
      // h for next step: sc1 write-through, ack'd at LLC when vmcnt drains
      unsigned short* hp = (unsigned short*)(Hh +
          ((size_t)((t + 1) & 1) * B_ + bb) * H_ + hcol);
      __hip_atomic_store(hp, f2bf(h), __ATOMIC_RELAXED, __HIP_MEMORY_SCOPE_AGENT);
      hbuf[m][bb][t & 31] = h;
      if ((t & 31) == 31) {  // coalesced 128 B burst per thread
        float* orow = out + ((size_t)bb * H_ + hcol) * T_ + (t - 31);
#pragma unroll
        for (int tt = 0; tt < 32; tt += 4) {
          float4 v = {hbuf[m][bb][tt], hbuf[m][bb][tt + 1],
                      hbuf[m][bb][tt + 2], hbuf[m][bb][tt + 3]};
          *(float4*)(orow + tt) = v;
        }
      }
    }
    __syncthreads();  // drains all waves' vmcnt: h stores ack'd at LLC
    if (tid == 0)
      __hip_atomic_store(&flags[nb], (unsigned int)(t + 1), __ATOMIC_RELAXED,
                         __HIP_MEMORY_SCOPE_AGENT);
  }
  if (tid < 256) out[(size_t)B_ * H_ * T_ + (size_t)bb * H_ + hcol] = creg;
}

extern "C" void kernel_launch(void* const* d_in, const int* in_sizes, int n_in,
                              void* d_out, int out_size, void* d_ws, size_t ws_size,
                              hipStream_t stream) {
  const float* x  = (const float*)d_in[0];
  const float* y  = (const float*)d_in[2];
  const float* Wf = (const float*)d_in[3];  const float* bf = (const float*)d_in[4];
  const float* Wi = (const float*)d_in[5];  const float* bi = (const float*)d_in[6];
  const float* Wu = (const float*)d_in[7];  const float* bu = (const float*)d_in[8];
  const float* Wo = (const float*)d_in[9];  const float* bo = (const float*)d_in[10];
  float* out = (float*)d_out;

  char* p = (char*)d_ws;
  ushort* Bp = (ushort*)p;        p += (size_t)256 * NKK_ * 64 * 8 * 2;  // 10.49 MB
  ushort* Xall = (ushort*)p;      p += (size_t)T_ * B_ * 256 * 2;        // 8.39 MB
  unsigned int* flags = (unsigned int*)p; p += 4096;                     // 256 words
  ushort* Hh = (ushort*)p;        // 2 slots x 128 KB ping-pong

  prep_weights<<<(256 * NKK_ * 64) / 256, 256, 0, stream>>>(Wf, Wi, Wu, Wo, Bp);
  build_X<<<B_ * 8, 256, 0, stream>>>(x, y, Xall);
  hipMemsetAsync(flags, 0, 4096, stream);
  hipMemsetAsync(Hh, 0, (size_t)B_ * H_ * 2, stream);  // slot 0 = h_{-1} = 0

  lstm_persist<<<NB_, 1024, 0, stream>>>(Xall, Bp, bf, bi, bu, bo, Hh, out, flags);
}